// Round 8
// baseline (304.462 us; speedup 1.0000x reference)
//
#include <hip/hip_runtime.h>
#include <stdint.h>

#define IDIM 2048
#define HDIM 2048
#define CDIM 4096
#define BDIM 4096
#define KDIM 4096

typedef float f32x4 __attribute__((ext_vector_type(4)));
typedef short s16x8 __attribute__((ext_vector_type(8)));
typedef unsigned short u16;
typedef u16 u16x8 __attribute__((ext_vector_type(8)));

__device__ __forceinline__ u16 f2bf(float f) {
    union { float f; uint32_t u; } v; v.f = f;
    uint32_t r = v.u + 0x7fffu + ((v.u >> 16) & 1u);  // round-to-nearest-even
    return (u16)(r >> 16);
}

__device__ __forceinline__ u16x8 cvt8(float4 v0, float4 v1) {
    u16x8 o;
    o[0] = f2bf(v0.x); o[1] = f2bf(v0.y); o[2] = f2bf(v0.z); o[3] = f2bf(v0.w);
    o[4] = f2bf(v1.x); o[5] = f2bf(v1.y); o[6] = f2bf(v1.z); o[7] = f2bf(v1.w);
    return o;
}

__device__ __forceinline__ void gload_lds16(const void* g, void* l) {
    __builtin_amdgcn_global_load_lds(
        (__attribute__((address_space(1))) void*)g,
        (__attribute__((address_space(3))) void*)l,
        16, 0, 0);
}

// merged prep: Wu + Ws + Wp cvt (3 x 1M groups) + pack_combined (2M groups).
// (round-7: folding Wp into GEMM1's tail cost its FULL price — serial per
// block, no overlap. Here it shares one launch + streams at HBM BW.)
__global__ void prep_kernel(const float* __restrict__ x, const float* __restrict__ h,
                            const float* __restrict__ Wu, const float* __restrict__ Ws,
                            const float* __restrict__ Wp,
                            u16* __restrict__ comb, u16* __restrict__ newc,
                            u16* __restrict__ wpack) {
    const int WCNT = (HDIM * CDIM) / 8;             // 1M groups per weight
    int i = blockIdx.x * blockDim.x + threadIdx.x;  // 0..5M-1
    if (i < 3 * WCNT) {
        const float* src; size_t off; int g;
        if (i < WCNT)          { src = Wu; off = 0;                        g = i; }
        else if (i < 2 * WCNT) { src = Ws; off = (size_t)HDIM * CDIM;      g = i - WCNT; }
        else                   { src = Wp; off = (size_t)2 * HDIM * CDIM;  g = i - 2 * WCNT; }
        const float4* s4 = (const float4*)src;
        ((u16x8*)(wpack + off))[g] = cvt8(s4[2 * g], s4[2 * g + 1]);
    } else {
        const int p = i - 3 * WCNT;                 // 0..2M-1
        const int b = p >> 9;                       // CDIM/8 == 512
        const int c = (p & 511) * 8;
        const float* src = (c < IDIM) ? (x + (size_t)b * IDIM + c)
                                      : (h + (size_t)b * HDIM + (c - IDIM));
        u16x8 o = cvt8(((const float4*)src)[0], ((const float4*)src)[1]);
        *(u16x8*)(comb + (size_t)b * CDIM + c) = o;
        if (c < IDIM) *(u16x8*)(newc + (size_t)b * CDIM + c) = o;
    }
}

// ---------------------------------------------------------------------------
// GEMM1 v4: wave-tile experiment. Same 2-barrier m97 skeleton + grid (32x32 =
// 1024 blocks, 4/CU), but 2 waves/block (128 thr), wave tile 64(M) x 128(N):
// 42.7 FLOP/LDS-byte vs the 64x64 tile's 32 — if the structure is LDS-read-BW
// bound (256KB/CU/step ~ 2000cy > 620cy MFMA at 16 waves/CU), this raises the
// ceiling 1.33x. acc[4][8] = 128 VGPR; launch_bounds(128,2) caps 256 VGPR.
// Staging = GEMM2-v3's proven 128-thread pattern (16-row chunks).
// Epilogue: v=sigmoid(acc+bias); col<HDIM -> newc[r][IDIM+col]=bf16(h*v);
//           col>=HDIM -> Sout[r][col-HDIM]=v
// ---------------------------------------------------------------------------
__global__ __launch_bounds__(128, 2) void gemm_bt1(
        const u16* __restrict__ A, const u16* __restrict__ Bm,
        const float* __restrict__ h,
        const float* __restrict__ bias0, const float* __restrict__ bias1,
        float* __restrict__ Sout, u16* __restrict__ newc) {
    constexpr int BM = 128, BN = 128, BK = 64;
    const int tid  = threadIdx.x;                   // 0..127
    const int lane = tid & 63;
    const int wave = tid >> 6;                      // M-split: rows wave*64..+63
    const int bm = blockIdx.y * BM;
    const int bn = blockIdx.x * BN;

    __shared__ __align__(16) u16 lA[BM * BK];       // 16KB
    __shared__ __align__(16) u16 lB[BN * BK];       // 16KB

    f32x4 acc[4][8] = {};

    // staging: chunk = 16 rows x 64k = 2KB = 128 threads x 16B.
    // thread t -> row c*16 + (t>>3), slot t&7, src swizzle (t&7)^(row&7).
    // dest wave-uniform base &l[(c*16 + wave*8)*64], HW adds lane*16B.
    const int srow = tid >> 3;                      // 0..15
    const int ssw  = ((tid & 7) ^ (srow & 7)) << 3;

    auto stage = [&](int k0) {
        #pragma unroll
        for (int c = 0; c < 8; ++c)                 // A: 128 rows
            gload_lds16(A + (size_t)(bm + c * 16 + srow) * KDIM + k0 + ssw,
                        &lA[(c * 16 + wave * 8) * 64]);
        #pragma unroll
        for (int c = 0; c < 8; ++c)                 // B: 128 rows
            gload_lds16(Bm + (size_t)(bn + c * 16 + srow) * KDIM + k0 + ssw,
                        &lB[(c * 16 + wave * 8) * 64]);
    };

    stage(0);
    constexpr int NT = KDIM / BK;
    for (int kt = 0; kt < NT; ++kt) {
        __syncthreads();   // drains global_load_lds (vmcnt) + all waves ready
        #pragma unroll
        for (int ks = 0; ks < 2; ++ks) {
            s16x8 af[4], bfr[8];
            #pragma unroll
            for (int m = 0; m < 4; ++m) {
                const int row = wave * 64 + m * 16 + (lane & 15);
                const int j   = ks * 4 + (lane >> 4);
                af[m] = *(const s16x8*)&lA[row * 64 + ((j ^ (row & 7)) << 3)];
            }
            #pragma unroll
            for (int n = 0; n < 8; ++n) {
                const int row = n * 16 + (lane & 15);
                const int j   = ks * 4 + (lane >> 4);
                bfr[n] = *(const s16x8*)&lB[row * 64 + ((j ^ (row & 7)) << 3)];
            }
            #pragma unroll
            for (int m = 0; m < 4; ++m)
                #pragma unroll
                for (int n = 0; n < 8; ++n)
                    acc[m][n] = __builtin_amdgcn_mfma_f32_16x16x32_bf16(
                        af[m], bfr[n], acc[m][n], 0, 0, 0);
        }
        __syncthreads();   // all reads done before restage
        if (kt + 1 < NT) stage((kt + 1) * BK);
    }

    // epilogue: D layout col = lane&15, row = (lane>>4)*4 + reg (m89-verified)
    #pragma unroll
    for (int m = 0; m < 4; ++m) {
        const int r0 = bm + wave * 64 + m * 16 + ((lane >> 4) << 2);
        #pragma unroll
        for (int n = 0; n < 8; ++n) {
            const int col = bn + n * 16 + (lane & 15);
            #pragma unroll
            for (int j = 0; j < 4; ++j) {
                const int r = r0 + j;
                const float v = acc[m][n][j];
                const float bv = (col < HDIM) ? bias0[col] : bias1[col - HDIM];
                const float sgm = 1.0f / (1.0f + __expf(-(v + bv)));
                if (col < HDIM) {
                    const float hv = h[(size_t)r * HDIM + col];
                    newc[(size_t)r * CDIM + IDIM + col] = f2bf(hv * sgm);
                } else {
                    Sout[(size_t)r * HDIM + (col - HDIM)] = sgm;
                }
            }
        }
    }
}

// ---------------------------------------------------------------------------
// GEMM2 v3 (round-7, ~95us): 128x64 block, BK=64, 2 waves M-split, wave tile
// 64x64. Grid 32x32 = 1024 blocks. UNCHANGED this round (isolate GEMM1 exp).
// Epilogue: p=tanh(acc+bias); s=Sout[r][col]; Sout[r][col]=h*(1-s)+p*s
// ---------------------------------------------------------------------------
__global__ __launch_bounds__(128, 3) void gemm_bt2(
        const u16* __restrict__ A, const u16* __restrict__ Bm,
        const float* __restrict__ h, const float* __restrict__ bias0,
        float* __restrict__ Sout) {
    constexpr int BM = 128, BN = 64, BK = 64;
    const int tid  = threadIdx.x;                   // 0..127
    const int lane = tid & 63;
    const int wave = tid >> 6;                      // M-split: rows wave*64..+63
    const int bm = blockIdx.y * BM;
    const int bn = blockIdx.x * BN;

    __shared__ __align__(16) u16 lA[BM * BK];       // 16KB
    __shared__ __align__(16) u16 lB[BN * BK];       // 8KB

    f32x4 acc[4][4] = {};

    const int srow = tid >> 3;                      // 0..15
    const int ssw  = ((tid & 7) ^ (srow & 7)) << 3;

    auto stage = [&](int k0) {
        #pragma unroll
        for (int c = 0; c < 8; ++c)                 // A: 128 rows
            gload_lds16(A + (size_t)(bm + c * 16 + srow) * KDIM + k0 + ssw,
                        &lA[(c * 16 + wave * 8) * 64]);
        #pragma unroll
        for (int c = 0; c < 4; ++c)                 // B: 64 rows
            gload_lds16(Bm + (size_t)(bn + c * 16 + srow) * KDIM + k0 + ssw,
                        &lB[(c * 16 + wave * 8) * 64]);
    };

    stage(0);
    constexpr int NT = KDIM / BK;
    for (int kt = 0; kt < NT; ++kt) {
        __syncthreads();
        #pragma unroll
        for (int ks = 0; ks < 2; ++ks) {
            s16x8 af[4], bfr[4];
            #pragma unroll
            for (int m = 0; m < 4; ++m) {
                const int row = wave * 64 + m * 16 + (lane & 15);
                const int j   = ks * 4 + (lane >> 4);
                af[m] = *(const s16x8*)&lA[row * 64 + ((j ^ (row & 7)) << 3)];
            }
            #pragma unroll
            for (int n = 0; n < 4; ++n) {
                const int row = n * 16 + (lane & 15);
                const int j   = ks * 4 + (lane >> 4);
                bfr[n] = *(const s16x8*)&lB[row * 64 + ((j ^ (row & 7)) << 3)];
            }
            #pragma unroll
            for (int m = 0; m < 4; ++m)
                #pragma unroll
                for (int n = 0; n < 4; ++n)
                    acc[m][n] = __builtin_amdgcn_mfma_f32_16x16x32_bf16(
                        af[m], bfr[n], acc[m][n], 0, 0, 0);
        }
        __syncthreads();
        if (kt + 1 < NT) stage((kt + 1) * BK);
    }

    #pragma unroll
    for (int m = 0; m < 4; ++m) {
        const int r0 = bm + wave * 64 + m * 16 + ((lane >> 4) << 2);
        #pragma unroll
        for (int n = 0; n < 4; ++n) {
            const int col = bn + n * 16 + (lane & 15);
            #pragma unroll
            for (int j = 0; j < 4; ++j) {
                const int r = r0 + j;
                const float p = tanhf(acc[m][n][j] + bias0[col]);
                const size_t idx = (size_t)r * HDIM + col;
                const float s  = Sout[idx];
                const float hv = h[idx];
                Sout[idx] = hv * (1.0f - s) + p * s;
            }
        }
    }
}

extern "C" void kernel_launch(void* const* d_in, const int* in_sizes, int n_in,
                              void* d_out, int out_size, void* d_ws, size_t ws_size,
                              hipStream_t stream) {
    (void)in_sizes; (void)n_in; (void)out_size; (void)ws_size;
    const float* x  = (const float*)d_in[0];
    const float* h  = (const float*)d_in[1];
    const float* Wu = (const float*)d_in[2];
    const float* bu = (const float*)d_in[3];
    const float* Ws = (const float*)d_in[4];
    const float* bs = (const float*)d_in[5];
    const float* Wp = (const float*)d_in[6];
    const float* bp = (const float*)d_in[7];
    float* out = (float*)d_out;

    // workspace layout (bf16 elements): 112 MB total
    u16* comb  = (u16*)d_ws;                            // [BDIM][CDIM]   32 MB
    u16* newc  = comb  + (size_t)BDIM * CDIM;           // [BDIM][CDIM]   32 MB
    u16* wpack = newc  + (size_t)BDIM * CDIM;           // [2*HDIM][CDIM] 32 MB
    u16* wpred = wpack + (size_t)2 * HDIM * CDIM;       // [HDIM][CDIM]   16 MB

    // prep: Wu+Ws+Wp cvt + pack_combined, one kernel (5M groups of 8 elems)
    const int ngrp = 3 * ((HDIM * CDIM) / 8) + (BDIM * CDIM) / 8;   // 5M
    prep_kernel<<<ngrp / 256, 256, 0, stream>>>(x, h, Wu, Ws, Wp, comb, newc, wpack);

    // GEMM1: [x,h] @ [Wu;Ws]^T -> sigmoid -> updated (bf16 into newc) + S (f32 into out)
    gemm_bt1<<<dim3(CDIM / 128, BDIM / 128), 128, 0, stream>>>(
        comb, wpack, h, bu, bs, out, newc);
    // GEMM2: [x,updated] @ Wp^T -> tanh -> h_new (f32 into out, reading S in place)
    gemm_bt2<<<dim3(HDIM / 64, BDIM / 128), 128, 0, stream>>>(
        newc, wpred, h, bp, out);
}

// Round 9
// 283.415 us; speedup vs baseline: 1.0743x; 1.0743x over previous
//
#include <hip/hip_runtime.h>
#include <stdint.h>

#define IDIM 2048
#define HDIM 2048
#define CDIM 4096
#define BDIM 4096
#define KDIM 4096

typedef float f32x4 __attribute__((ext_vector_type(4)));
typedef short s16x8 __attribute__((ext_vector_type(8)));
typedef unsigned short u16;
typedef u16 u16x8 __attribute__((ext_vector_type(8)));

__device__ __forceinline__ u16 f2bf(float f) {
    union { float f; uint32_t u; } v; v.f = f;
    uint32_t r = v.u + 0x7fffu + ((v.u >> 16) & 1u);  // round-to-nearest-even
    return (u16)(r >> 16);
}

__device__ __forceinline__ float b2f(u16 b) {
    union { uint32_t u; float f; } v; v.u = ((uint32_t)b) << 16;
    return v.f;
}

__device__ __forceinline__ u16x8 cvt8(float4 v0, float4 v1) {
    u16x8 o;
    o[0] = f2bf(v0.x); o[1] = f2bf(v0.y); o[2] = f2bf(v0.z); o[3] = f2bf(v0.w);
    o[4] = f2bf(v1.x); o[5] = f2bf(v1.y); o[6] = f2bf(v1.z); o[7] = f2bf(v1.w);
    return o;
}

__device__ __forceinline__ void gload_lds16(const void* g, void* l) {
    __builtin_amdgcn_global_load_lds(
        (__attribute__((address_space(1))) void*)g,
        (__attribute__((address_space(3))) void*)l,
        16, 0, 0);
}

// merged prep: Wu + Ws + Wp cvt (3 x 1M groups) + pack [x,h] -> comb (2M).
// (newc dropped: GEMM2 stages x-half from comb, upd-half from the compact
// upd buffer GEMM1 writes — saves 16MB of prep write.)
__global__ void prep_kernel(const float* __restrict__ x, const float* __restrict__ h,
                            const float* __restrict__ Wu, const float* __restrict__ Ws,
                            const float* __restrict__ Wp,
                            u16* __restrict__ comb, u16* __restrict__ wpack) {
    const int WCNT = (HDIM * CDIM) / 8;             // 1M groups per weight
    int i = blockIdx.x * blockDim.x + threadIdx.x;  // 0..5M-1
    if (i < 3 * WCNT) {
        const float* src; size_t off; int g;
        if (i < WCNT)          { src = Wu; off = 0;                        g = i; }
        else if (i < 2 * WCNT) { src = Ws; off = (size_t)HDIM * CDIM;      g = i - WCNT; }
        else                   { src = Wp; off = (size_t)2 * HDIM * CDIM;  g = i - 2 * WCNT; }
        const float4* s4 = (const float4*)src;
        ((u16x8*)(wpack + off))[g] = cvt8(s4[2 * g], s4[2 * g + 1]);
    } else {
        const int p = i - 3 * WCNT;                 // 0..2M-1
        const int b = p >> 9;                       // CDIM/8 == 512
        const int c = (p & 511) * 8;
        const float* src = (c < IDIM) ? (x + (size_t)b * IDIM + c)
                                      : (h + (size_t)b * HDIM + (c - IDIM));
        u16x8 o = cvt8(((const float4*)src)[0], ((const float4*)src)[1]);
        *(u16x8*)(comb + (size_t)b * CDIM + c) = o;
    }
}

// ---------------------------------------------------------------------------
// GEMM1 (proven m97, 149us/922TF — round-8 confirmed this config is a local
// optimum: all neighbors in {wave-tile, BK, waves, split-K, phasing} lost).
// 128x128 tile, BK=64, 4 waves 2x2, wave tile 64x64, 16 waves/CU.
// Epilogue (bf16 traffic cut): v=sigmoid(acc+bias);
//   col<HDIM  -> upd[r][col]   = bf16(h*v)   (h re-read as bf16 from comb)
//   col>=HDIM -> S[r][col-HDIM] = bf16(v)
// ---------------------------------------------------------------------------
__global__ void gemm_bt1(const u16* __restrict__ A, const u16* __restrict__ Bm,
                         const float* __restrict__ bias0, const float* __restrict__ bias1,
                         u16* __restrict__ upd, u16* __restrict__ S) {
    constexpr int BM = 128, BK = 64;
    const int tid  = threadIdx.x;
    const int lane = tid & 63;
    const int wave = tid >> 6;
    const int wr = wave >> 1, wc = wave & 1;
    const int bm = blockIdx.y * BM;
    const int bn = blockIdx.x * BM;

    __shared__ __align__(16) u16 lA[BM * BK];
    __shared__ __align__(16) u16 lB[BM * BK];

    f32x4 acc[4][4] = {};

    const int srow = wave * 32 + (lane >> 3);       // staged row (per i: +8*i)
    const int sg   = (lane & 7) ^ (lane >> 3);      // swizzled source k-slot

    auto stage = [&](int k0) {
        #pragma unroll
        for (int i = 0; i < 4; ++i) {
            const int r = srow + i * 8;
            gload_lds16(A  + (size_t)(bm + r) * KDIM + k0 + sg * 8,
                        &lA[(wave * 32 + i * 8) * 64]);
            gload_lds16(Bm + (size_t)(bn + r) * KDIM + k0 + sg * 8,
                        &lB[(wave * 32 + i * 8) * 64]);
        }
    };

    stage(0);
    constexpr int NT = KDIM / BK;
    for (int kt = 0; kt < NT; ++kt) {
        __syncthreads();   // drains global_load_lds (vmcnt) + all waves ready
        #pragma unroll
        for (int ks = 0; ks < 2; ++ks) {
            s16x8 af[4], bfr[4];
            #pragma unroll
            for (int m = 0; m < 4; ++m) {
                const int row = wr * 64 + m * 16 + (lane & 15);
                const int j   = ks * 4 + (lane >> 4);
                af[m] = *(const s16x8*)&lA[row * 64 + ((j ^ (row & 7)) << 3)];
            }
            #pragma unroll
            for (int n = 0; n < 4; ++n) {
                const int row = wc * 64 + n * 16 + (lane & 15);
                const int j   = ks * 4 + (lane >> 4);
                bfr[n] = *(const s16x8*)&lB[row * 64 + ((j ^ (row & 7)) << 3)];
            }
            #pragma unroll
            for (int m = 0; m < 4; ++m)
                #pragma unroll
                for (int n = 0; n < 4; ++n)
                    acc[m][n] = __builtin_amdgcn_mfma_f32_16x16x32_bf16(
                        af[m], bfr[n], acc[m][n], 0, 0, 0);
        }
        __syncthreads();   // all reads done before restage
        if (kt + 1 < NT) stage((kt + 1) * BK);
    }

    // epilogue: D layout col = lane&15, row = (lane>>4)*4 + reg (m89-verified)
    #pragma unroll
    for (int m = 0; m < 4; ++m) {
        const int r0 = bm + wr * 64 + m * 16 + ((lane >> 4) << 2);
        #pragma unroll
        for (int n = 0; n < 4; ++n) {
            const int col = bn + wc * 64 + n * 16 + (lane & 15);
            #pragma unroll
            for (int j = 0; j < 4; ++j) {
                const int r = r0 + j;
                const float v = acc[m][n][j];
                const float bv = (col < HDIM) ? bias0[col] : bias1[col - HDIM];
                const float sgm = 1.0f / (1.0f + __expf(-(v + bv)));
                if (col < HDIM) {
                    const float hv = b2f(A[(size_t)r * CDIM + IDIM + col]);  // h (bf16, from comb)
                    upd[(size_t)r * HDIM + col] = f2bf(hv * sgm);
                } else {
                    S[(size_t)r * HDIM + (col - HDIM)] = f2bf(sgm);
                }
            }
        }
    }
}

// ---------------------------------------------------------------------------
// GEMM2 v3 (round-7 proven ~95us): 128x64 block, BK=64, 2 waves M-split,
// wave tile 64x64, grid 32x32 = 1024 blocks. A-operand split-source:
// k<2048 from comb's x-half (stride CDIM), k>=2048 from upd (stride HDIM).
// Epilogue: p=tanh(acc+bias); s=S (bf16); h from comb's h-half (bf16);
//           out[r][col] = h*(1-s)+p*s  (f32)
// ---------------------------------------------------------------------------
__global__ __launch_bounds__(128, 3) void gemm_bt2(
        const u16* __restrict__ comb, const u16* __restrict__ upd,
        const u16* __restrict__ Bm, const float* __restrict__ bias0,
        const u16* __restrict__ S, float* __restrict__ out) {
    constexpr int BM = 128, BN = 64, BK = 64;
    const int tid  = threadIdx.x;                   // 0..127
    const int lane = tid & 63;
    const int wave = tid >> 6;                      // M-split: rows wave*64..+63
    const int bm = blockIdx.y * BM;
    const int bn = blockIdx.x * BN;

    __shared__ __align__(16) u16 lA[BM * BK];       // 16KB
    __shared__ __align__(16) u16 lB[BN * BK];       // 8KB

    f32x4 acc[4][4] = {};

    const int srow = tid >> 3;                      // 0..15
    const int ssw  = ((tid & 7) ^ (srow & 7)) << 3;

    auto stage = [&](int k0) {
        const bool inX = (k0 < IDIM);
        #pragma unroll
        for (int c = 0; c < 8; ++c) {               // A: 128 rows
            const int r = bm + c * 16 + srow;
            const u16* src = inX ? (comb + (size_t)r * CDIM + k0 + ssw)
                                 : (upd  + (size_t)r * HDIM + (k0 - IDIM) + ssw);
            gload_lds16(src, &lA[(c * 16 + wave * 8) * 64]);
        }
        #pragma unroll
        for (int c = 0; c < 4; ++c)                 // B: 64 rows
            gload_lds16(Bm + (size_t)(bn + c * 16 + srow) * KDIM + k0 + ssw,
                        &lB[(c * 16 + wave * 8) * 64]);
    };

    stage(0);
    constexpr int NT = KDIM / BK;
    for (int kt = 0; kt < NT; ++kt) {
        __syncthreads();
        #pragma unroll
        for (int ks = 0; ks < 2; ++ks) {
            s16x8 af[4], bfr[4];
            #pragma unroll
            for (int m = 0; m < 4; ++m) {
                const int row = wave * 64 + m * 16 + (lane & 15);
                const int j   = ks * 4 + (lane >> 4);
                af[m] = *(const s16x8*)&lA[row * 64 + ((j ^ (row & 7)) << 3)];
            }
            #pragma unroll
            for (int n = 0; n < 4; ++n) {
                const int row = n * 16 + (lane & 15);
                const int j   = ks * 4 + (lane >> 4);
                bfr[n] = *(const s16x8*)&lB[row * 64 + ((j ^ (row & 7)) << 3)];
            }
            #pragma unroll
            for (int m = 0; m < 4; ++m)
                #pragma unroll
                for (int n = 0; n < 4; ++n)
                    acc[m][n] = __builtin_amdgcn_mfma_f32_16x16x32_bf16(
                        af[m], bfr[n], acc[m][n], 0, 0, 0);
        }
        __syncthreads();
        if (kt + 1 < NT) stage((kt + 1) * BK);
    }

    #pragma unroll
    for (int m = 0; m < 4; ++m) {
        const int r0 = bm + wave * 64 + m * 16 + ((lane >> 4) << 2);
        #pragma unroll
        for (int n = 0; n < 4; ++n) {
            const int col = bn + n * 16 + (lane & 15);
            #pragma unroll
            for (int j = 0; j < 4; ++j) {
                const int r = r0 + j;
                const float p = tanhf(acc[m][n][j] + bias0[col]);
                const size_t idx = (size_t)r * HDIM + col;
                const float s  = b2f(S[idx]);
                const float hv = b2f(comb[(size_t)r * CDIM + IDIM + col]);
                out[idx] = hv * (1.0f - s) + p * s;
            }
        }
    }
}

extern "C" void kernel_launch(void* const* d_in, const int* in_sizes, int n_in,
                              void* d_out, int out_size, void* d_ws, size_t ws_size,
                              hipStream_t stream) {
    (void)in_sizes; (void)n_in; (void)out_size; (void)ws_size;
    const float* x  = (const float*)d_in[0];
    const float* h  = (const float*)d_in[1];
    const float* Wu = (const float*)d_in[2];
    const float* bu = (const float*)d_in[3];
    const float* Ws = (const float*)d_in[4];
    const float* bs = (const float*)d_in[5];
    const float* Wp = (const float*)d_in[6];
    const float* bp = (const float*)d_in[7];
    float* out = (float*)d_out;

    // workspace layout (bf16 elements): 112 MB total
    u16* comb  = (u16*)d_ws;                            // [BDIM][CDIM]   32 MB
    u16* wpack = comb  + (size_t)BDIM * CDIM;           // [2H+H][CDIM]   48 MB (Wu;Ws;Wp)
    u16* wpred = wpack + (size_t)2 * HDIM * CDIM;       //   (Wp part of wpack)
    u16* upd   = wpack + (size_t)3 * HDIM * CDIM;       // [BDIM][HDIM]   16 MB
    u16* S     = upd   + (size_t)BDIM * HDIM;           // [BDIM][HDIM]   16 MB

    // prep: Wu+Ws+Wp cvt + pack [x,h]->comb, one kernel (5M groups of 8)
    const int ngrp = 3 * ((HDIM * CDIM) / 8) + (BDIM * CDIM) / 8;   // 5M
    prep_kernel<<<ngrp / 256, 256, 0, stream>>>(x, h, Wu, Ws, Wp, comb, wpack);

    // GEMM1: comb @ [Wu;Ws]^T -> sigmoid -> upd (bf16) + S (bf16)
    gemm_bt1<<<dim3(CDIM / 128, BDIM / 128), 256, 0, stream>>>(
        comb, wpack, bu, bs, upd, S);
    // GEMM2: [x,upd] @ Wp^T -> tanh -> h_new (f32 out)
    gemm_bt2<<<dim3(HDIM / 64, BDIM / 128), 128, 0, stream>>>(
        comb, upd, wpred, bp, S, out);
}